// Round 6
// baseline (244.773 us; speedup 1.0000x reference)
//
#include <hip/hip_runtime.h>
#include <math.h>

namespace {

constexpr int L   = 200;
constexpr int E   = 64;
constexpr int H1N = 80;
constexpr int H2N = 40;

using short8 = __attribute__((ext_vector_type(8))) short;
using f32x4  = __attribute__((ext_vector_type(4))) float;

__device__ inline unsigned short f2bf(float f) {
    union { float f; unsigned u; } x{f};
    unsigned r = x.u + 0x7fffu + ((x.u >> 16) & 1u);   // RNE
    return (unsigned short)(r >> 16);
}
__device__ inline float bf2f(short s) {
    union { unsigned u; float f; } x;
    x.u = ((unsigned)(unsigned short)s) << 16;
    return x.f;
}

// DPP row_ror add: x += ror_n(x) within each 16-lane row (VALU pipe, no LDS)
#define ROR_ADD(x, CTRL) do {                                                   \
    int _t = __builtin_amdgcn_update_dpp(0, __builtin_bit_cast(int, (x)),       \
                                         (CTRL), 0xf, 0xf, true);               \
    (x) += __builtin_bit_cast(float, _t); } while (0)

// ---- workspace layout (bytes) ----
constexpr int WS_ABF  = 0;        // bf16[1280*8] GEMM1 B-frags (K=128: A | C)
constexpr int WS_W2F  = 20480;    // bf16[576*8]  GEMM2 B-frags
constexpr int WS_FLAG = 29696;    // int: 1 if mask is int32, 0 if bytes
constexpr int WS_CQ   = 29952;    // f32 [B][80]  cq

// Prep: frag packing + cq GEMV + mask-dtype sniff, id-partitioned.
__global__ void k0_prep(const float* __restrict__ W1,
                        const float* __restrict__ W2,
                        const float* __restrict__ q,
                        const float* __restrict__ b1,
                        const void* __restrict__ mask,
                        unsigned short* __restrict__ Abf,
                        unsigned short* __restrict__ W2f,
                        float* __restrict__ cq_all,
                        int* __restrict__ flagG, int B)
{
    const int id = blockIdx.x * 256 + threadIdx.x;
    if (id < 1280) {
        // frag u=(nt*4+ks)*64+lane; ks 0,1 -> A=(W1_k-W1_d); ks 2,3 -> C=W1_p
        const int u  = id, cc = u >> 6, ln = u & 63;
        const int nt = cc >> 2, ks = cc & 3;
        const int j  = nt * 16 + (ln & 15);
        const int i0 = (ks & 1) * 32 + (ln >> 4) * 8;
        #pragma unroll
        for (int e = 0; e < 8; ++e) {
            const int i = i0 + e;
            const float v = (ks < 2)
                ? (W1[(E + i) * H1N + j] - W1[(2 * E + i) * H1N + j])
                : W1[(3 * E + i) * H1N + j];
            Abf[u * 8 + e] = f2bf(v);
        }
    } else if (id < 1856) {
        const int u   = id - 1280, cc = u >> 6, ln = u & 63;
        const int nt2 = cc / 3, ks2 = cc % 3;
        const int n   = nt2 * 16 + (ln & 15);
        const int j0  = ks2 * 32 + (ln >> 4) * 8;
        #pragma unroll
        for (int e = 0; e < 8; ++e) {
            const int j = j0 + e;
            W2f[u * 8 + e] = (j < H1N && n < H2N) ? f2bf(W2[j * H2N + n])
                                                  : (unsigned short)0;
        }
    } else {
        const int t = id - 1856;
        if (t > B * 20) return;
        if (t == B * 20) {
            // mask dtype sniff, ONCE for the whole launch (was per-block serial!)
            const unsigned char* mb = (const unsigned char*)mask;
            int isI32 = 1;
            for (int i = 0; i < 256; ++i)
                if ((i & 3) && mb[i]) { isI32 = 0; break; }
            flagG[0] = isI32;
            return;
        }
        const int b  = t / 20;
        const int jq = (t - b * 20) * 4;
        const float* qb = q + (size_t)b * E;
        float4 a = *(const float4*)(b1 + jq);
        #pragma unroll 8
        for (int i = 0; i < E; ++i) {
            const float qv = qb[i];
            const float4 wa = *(const float4*)(W1 + i * H1N + jq);
            const float4 wb = *(const float4*)(W1 + (2 * E + i) * H1N + jq);
            a.x += qv * (wa.x + wb.x);
            a.y += qv * (wa.y + wb.y);
            a.z += qv * (wa.z + wb.z);
            a.w += qv * (wa.w + wb.w);
        }
        *(float4*)(cq_all + (size_t)b * H1N + jq) = a;
    }
}

// build ak (bf16 of K) and aq (bf16 of K*q) fragments from two float4 + packed q
#define MK_FRAGS(AK, AQ, A0, A1, KH)                                              \
    do {                                                                          \
        AK[0] = (short)f2bf(A0.x); AK[1] = (short)f2bf(A0.y);                     \
        AK[2] = (short)f2bf(A0.z); AK[3] = (short)f2bf(A0.w);                     \
        AK[4] = (short)f2bf(A1.x); AK[5] = (short)f2bf(A1.y);                     \
        AK[6] = (short)f2bf(A1.z); AK[7] = (short)f2bf(A1.w);                     \
        AQ[0] = (short)f2bf(A0.x * bf2f(qbf[KH][0]));                             \
        AQ[1] = (short)f2bf(A0.y * bf2f(qbf[KH][1]));                             \
        AQ[2] = (short)f2bf(A0.z * bf2f(qbf[KH][2]));                             \
        AQ[3] = (short)f2bf(A0.w * bf2f(qbf[KH][3]));                             \
        AQ[4] = (short)f2bf(A1.x * bf2f(qbf[KH][4]));                             \
        AQ[5] = (short)f2bf(A1.y * bf2f(qbf[KH][5]));                             \
        AQ[6] = (short)f2bf(A1.z * bf2f(qbf[KH][6]));                             \
        AQ[7] = (short)f2bf(A1.w * bf2f(qbf[KH][7]));                             \
    } while (0)

__global__ __launch_bounds__(256, 5)
void attn_main(const float* __restrict__ q,
               const float* __restrict__ kmat,
               const float* __restrict__ vmat,
               const void* __restrict__ mask,
               const float* __restrict__ b2,
               const float* __restrict__ Wf,
               const float* __restrict__ bfp,
               const unsigned short* __restrict__ AbfG,
               const unsigned short* __restrict__ W2fG,
               const float* __restrict__ cq_all,
               const int* __restrict__ flagG,
               float* __restrict__ out)
{
    const int tid  = threadIdx.x;
    const int lane = tid & 63;
    const int wv   = tid >> 6;
    const int g    = lane >> 4;
    const int c    = lane & 15;

    __shared__ unsigned short H1t[4][16][104];   // 13312 B (per-wave tiles)
    __shared__ float score[256];                 //  1024 B
    __shared__ float part_s[4][64];              //  1024 B
    __shared__ float red_s[8];

    const int bb = blockIdx.x;                   // one batch per BLOCK

    // per-wave H1t K-pad zero (cols 80..95)
    *(unsigned long long*)&H1t[wv][c][80 + g * 4] = 0ULL;

    // ---- per-batch setup (unconditional, no barriers) ----
    const float* qb = q + (size_t)bb * E;
    short8 qbf[2];
    #pragma unroll
    for (int kh = 0; kh < 2; ++kh) {
        const float4 t0 = *(const float4*)(qb + kh * 32 + g * 8);
        const float4 t1 = *(const float4*)(qb + kh * 32 + g * 8 + 4);
        short8 p;
        p[0] = (short)f2bf(t0.x); p[1] = (short)f2bf(t0.y);
        p[2] = (short)f2bf(t0.z); p[3] = (short)f2bf(t0.w);
        p[4] = (short)f2bf(t1.x); p[5] = (short)f2bf(t1.y);
        p[6] = (short)f2bf(t1.z); p[7] = (short)f2bf(t1.w);
        qbf[kh] = p;
    }
    float cqr[5];
    #pragma unroll
    for (int nt = 0; nt < 5; ++nt)
        cqr[nt] = cq_all[(size_t)bb * H1N + nt * 16 + c];
    float b2r[3], wfr[3];
    #pragma unroll
    for (int nt2 = 0; nt2 < 3; ++nt2) {
        const int nc = nt2 * 16 + c;
        b2r[nt2] = (nc < H2N) ? b2[nc] : 0.f;
        wfr[nt2] = (nc < H2N) ? Wf[nc] : 0.f;
    }
    const float bf0 = bfp[0];
    const short8* Ab  = (const short8*)AbfG;     // 20.5 KB, L1-resident
    const short8* W2v = (const short8*)W2fG;     //  9.2 KB, L1-resident
    const float*  kbase = kmat + (size_t)bb * (L * E);

    // ---- 13 tiles of 16 rows split across 4 waves (wave wv: t = wv, wv+4, ...) ----
    #pragma unroll 1
    for (int rt = 0; rt < 4; ++rt) {
        const int t = wv + 4 * rt;
        if (t < 13) {
            const float4* kp = (const float4*)(kbase + (size_t)min(16 * t + c, L - 1) * E);
            const float4 kb0 = kp[2 * g];
            const float4 kb1 = kp[2 * g + 1];
            const float4 kb2 = kp[8 + 2 * g];
            const float4 kb3 = kp[8 + 2 * g + 1];

            short8 ak0, aq0, ak1, aq1;
            MK_FRAGS(ak0, aq0, kb0, kb1, 0);
            MK_FRAGS(ak1, aq1, kb2, kb3, 1);

            f32x4 acc1[5];
            #pragma unroll
            for (int nt = 0; nt < 5; ++nt) acc1[nt] = f32x4{0.f, 0.f, 0.f, 0.f};
            #pragma unroll
            for (int nt = 0; nt < 5; ++nt) {
                acc1[nt] = __builtin_amdgcn_mfma_f32_16x16x32_bf16(ak0, Ab[(nt * 4 + 0) * 64 + lane], acc1[nt], 0, 0, 0);
                acc1[nt] = __builtin_amdgcn_mfma_f32_16x16x32_bf16(aq0, Ab[(nt * 4 + 2) * 64 + lane], acc1[nt], 0, 0, 0);
                acc1[nt] = __builtin_amdgcn_mfma_f32_16x16x32_bf16(ak1, Ab[(nt * 4 + 1) * 64 + lane], acc1[nt], 0, 0, 0);
                acc1[nt] = __builtin_amdgcn_mfma_f32_16x16x32_bf16(aq1, Ab[(nt * 4 + 3) * 64 + lane], acc1[nt], 0, 0, 0);
            }

            // H1 -> per-wave LDS tile (bf16), then GEMM2
            #pragma unroll
            for (int nt = 0; nt < 5; ++nt)
                #pragma unroll
                for (int r = 0; r < 4; ++r)
                    H1t[wv][4 * g + r][nt * 16 + c] = f2bf(acc1[nt][r] + cqr[nt]);

            f32x4 acc2[3];
            #pragma unroll
            for (int nt2 = 0; nt2 < 3; ++nt2) acc2[nt2] = f32x4{0.f, 0.f, 0.f, 0.f};
            #pragma unroll
            for (int ks2 = 0; ks2 < 3; ++ks2) {
                const short8 a2 = *(const short8*)&H1t[wv][c][ks2 * 32 + g * 8];
                #pragma unroll
                for (int nt2 = 0; nt2 < 3; ++nt2)
                    acc2[nt2] = __builtin_amdgcn_mfma_f32_16x16x32_bf16(a2, W2v[(nt2 * 3 + ks2) * 64 + lane], acc2[nt2], 0, 0, 0);
            }

            float pl0 = 0.f, pl1 = 0.f, pl2 = 0.f, pl3 = 0.f;
            #pragma unroll
            for (int nt2 = 0; nt2 < 3; ++nt2) {
                const float wfv = wfr[nt2], b2v = b2r[nt2];
                pl0 += wfv * __builtin_amdgcn_rcpf(1.f + __expf(-(acc2[nt2][0] + b2v)));
                pl1 += wfv * __builtin_amdgcn_rcpf(1.f + __expf(-(acc2[nt2][1] + b2v)));
                pl2 += wfv * __builtin_amdgcn_rcpf(1.f + __expf(-(acc2[nt2][2] + b2v)));
                pl3 += wfv * __builtin_amdgcn_rcpf(1.f + __expf(-(acc2[nt2][3] + b2v)));
            }
            ROR_ADD(pl0, 0x128); ROR_ADD(pl0, 0x124); ROR_ADD(pl0, 0x122); ROR_ADD(pl0, 0x121);
            ROR_ADD(pl1, 0x128); ROR_ADD(pl1, 0x124); ROR_ADD(pl1, 0x122); ROR_ADD(pl1, 0x121);
            ROR_ADD(pl2, 0x128); ROR_ADD(pl2, 0x124); ROR_ADD(pl2, 0x122); ROR_ADD(pl2, 0x121);
            ROR_ADD(pl3, 0x128); ROR_ADD(pl3, 0x124); ROR_ADD(pl3, 0x122); ROR_ADD(pl3, 0x121);
            const float myv = (c == 0) ? pl0 : (c == 1) ? pl1 : (c == 2) ? pl2 : pl3;
            if (c < 4) score[16 * t + 4 * g + c] = bf0 + myv;
        }
    }
    __syncthreads();

    // ---- block-wide masked softmax over L ----
    const int flagv = flagG[0];
    float logit = -INFINITY;
    if (tid < L) {
        logit = score[tid];
        const size_t mi = (size_t)bb * L + tid;
        const int mv = flagv ? ((const int*)mask)[mi]
                             : (int)((const unsigned char*)mask)[mi];
        if (mv != 0) logit = -INFINITY;
    }
    float m = logit;
    #pragma unroll
    for (int off = 32; off > 0; off >>= 1)
        m = fmaxf(m, __shfl_xor(m, off));
    if (lane == 0) red_s[wv] = m;
    __syncthreads();
    const float gmax = fmaxf(fmaxf(red_s[0], red_s[1]), fmaxf(red_s[2], red_s[3]));

    const float e = __expf(logit - gmax);
    score[tid] = e;
    float ssum = e;
    #pragma unroll
    for (int off = 32; off > 0; off >>= 1)
        ssum += __shfl_xor(ssum, off);
    if (lane == 0) red_s[4 + wv] = ssum;
    __syncthreads();
    const float inv = 1.0f / (red_s[4] + red_s[5] + red_s[6] + red_s[7]);

    // ---- PV: wave wv covers rows 16*ll + 4*wv + g; lane sums e=[4c,4c+4) ----
    f32x4 oa = f32x4{0.f, 0.f, 0.f, 0.f};
    const float* vb = vmat + (size_t)bb * (L * E);
    #pragma unroll
    for (int ll = 0; ll < 13; ++ll) {
        const int row = 16 * ll + 4 * wv + g;
        if (row < L) {
            const float sv = score[row];
            const float4 v4 = *(const float4*)(vb + row * E + c * 4);
            oa[0] += sv * v4.x; oa[1] += sv * v4.y;
            oa[2] += sv * v4.z; oa[3] += sv * v4.w;
        }
    }
    #pragma unroll
    for (int j = 0; j < 4; ++j) {
        oa[j] += __shfl_xor(oa[j], 16);
        oa[j] += __shfl_xor(oa[j], 32);
    }
    if (g == 0)
        *(float4*)&part_s[wv][4 * c] = make_float4(oa[0], oa[1], oa[2], oa[3]);
    __syncthreads();
    if (tid < 64) {
        const float o = (part_s[0][tid] + part_s[1][tid]
                       + part_s[2][tid] + part_s[3][tid]) * inv;
        out[(size_t)bb * E + tid] = o;
    }
}

} // namespace

extern "C" void kernel_launch(void* const* d_in, const int* in_sizes, int n_in,
                              void* d_out, int out_size, void* d_ws, size_t ws_size,
                              hipStream_t stream) {
    const float* q  = (const float*)d_in[0];
    const float* k  = (const float*)d_in[1];
    const float* v  = (const float*)d_in[2];
    const void*  mk = d_in[3];
    const float* W1 = (const float*)d_in[4];
    const float* b1 = (const float*)d_in[5];
    const float* W2 = (const float*)d_in[6];
    const float* b2 = (const float*)d_in[7];
    const float* Wf = (const float*)d_in[8];
    const float* bf = (const float*)d_in[9];
    float* out = (float*)d_out;

    const int B = in_sizes[0] / E;   // 4096

    char* ws = (char*)d_ws;
    unsigned short* Abf    = (unsigned short*)(ws + WS_ABF);
    unsigned short* W2f    = (unsigned short*)(ws + WS_W2F);
    int*            flagG  = (int*)(ws + WS_FLAG);
    float*          cq_all = (float*)(ws + WS_CQ);

    const int prep_ids = 1856 + B * 20 + 1;
    k0_prep<<<(prep_ids + 255) / 256, 256, 0, stream>>>(W1, W2, q, b1, mk,
                                                        Abf, W2f, cq_all, flagG, B);
    attn_main<<<B, 256, 0, stream>>>(q, k, v, mk, b2, Wf, bf,
                                     Abf, W2f, cq_all, flagG, out);
}